// Round 3
// baseline (1544.439 us; speedup 1.0000x reference)
//
#include <hip/hip_runtime.h>
#include <stdint.h>

#define HW 256
#define HWP 258
#define CH 32
#define CVN 64
#define NPIX (HW*HW)
#define KK 8
#define CSTR (HWP*HWP)

// PRNG hypothesis round 3:
//   MODE    = partitionable (default since JAX 0.4.36)
//   RANDINT = SPLIT: k1,k2 = split(key); higher=bits(k1,shape); lower=bits(k2,shape)
// (r1: single (2,)+shape draw — FAIL; r2: higher==lower ident — FAIL, both absmax 7.375)

// ---------------- Threefry-2x32 (JAX-compatible) ----------------
__host__ __device__ __forceinline__ void tf2x32(uint32_t k0, uint32_t k1,
                                                uint32_t x0, uint32_t x1,
                                                uint32_t &o0, uint32_t &o1) {
  const uint32_t ks2 = k0 ^ k1 ^ 0x1BD11BDAu;
  x0 += k0; x1 += k1;
#define TFR(r) x0 += x1; x1 = (x1 << (r)) | (x1 >> (32 - (r))); x1 ^= x0;
  TFR(13) TFR(15) TFR(26) TFR(6)
  x0 += k1;  x1 += ks2 + 1u;
  TFR(17) TFR(29) TFR(16) TFR(24)
  x0 += ks2; x1 += k0 + 2u;
  TFR(13) TFR(15) TFR(26) TFR(6)
  x0 += k0;  x1 += k1 + 3u;
  TFR(17) TFR(29) TFR(16) TFR(24)
  x0 += k1;  x1 += ks2 + 4u;
  TFR(13) TFR(15) TFR(26) TFR(6)
  x0 += ks2; x1 += k0 + 5u;
#undef TFR
  o0 = x0; o1 = x1;
}

// partitionable-mode random_bits (32-bit): v0 ^ v1 of enc(key, (0, idx))
__device__ __forceinline__ uint32_t tfbits(uint32_t k0, uint32_t k1, uint32_t idx) {
  uint32_t a, b;
  tf2x32(k0, k1, 0u, idx, a, b);
  return a ^ b;
}

// ---------------- zero-pad q,k into (C, 258, 258) ----------------
__global__ void pad_k(const float* __restrict__ q, const float* __restrict__ k,
                      float* __restrict__ qp, float* __restrict__ kp) {
  int idx = blockIdx.x * blockDim.x + threadIdx.x;
  const int total = 2 * CH * CSTR;
  if (idx >= total) return;
  int xx = idx % HWP;
  int t = idx / HWP;
  int yy = t % HWP;
  int bc = t / HWP;  // b*CH + c
  float qv = 0.f, kv = 0.f;
  if (xx >= 1 && xx <= HW && yy >= 1 && yy <= HW) {
    int src = (bc * HW + (yy - 1)) * HW + (xx - 1);
    qv = q[src];
    kv = k[src];
  }
  qp[idx] = qv;
  kp[idx] = kv;
}

// ---------------- patch cost, bit-exact XLA-CPU order ----------------
// cost = sum_{dy}{ S(dy,0)+S(dy,1)+S(dy,2) }, S = sequential sum over c of (q-k)^2
template<int NC>
__device__ __forceinline__ void patch_cost_multi(const float* __restrict__ qp,
                                                 const float* __restrict__ kp,
                                                 int y, int x,
                                                 const int* sy, const int* sx,
                                                 float* cost) {
#pragma clang fp contract(off)
#pragma unroll
  for (int j = 0; j < NC; j++) cost[j] = 0.f;
  for (int dy = 0; dy < 3; dy++) {
    float S0[NC], S1[NC], S2[NC];
#pragma unroll
    for (int j = 0; j < NC; j++) { S0[j] = 0.f; S1[j] = 0.f; S2[j] = 0.f; }
    const float* qr = qp + (y + dy) * HWP + x;
    int kb[NC];
#pragma unroll
    for (int j = 0; j < NC; j++) kb[j] = (sy[j] + dy) * HWP + sx[j];
    for (int c = 0; c < CH; c++) {
      float q0 = qr[0], q1 = qr[1], q2 = qr[2];
      const float* kc = kp + c * CSTR;
#pragma unroll
      for (int j = 0; j < NC; j++) {
        const float* kr = kc + kb[j];
        float d0 = q0 - kr[0]; float t0 = d0 * d0;
        float d1 = q1 - kr[1]; float t1 = d1 * d1;
        float d2 = q2 - kr[2]; float t2 = d2 * d2;
        S0[j] = S0[j] + t0;
        S1[j] = S1[j] + t1;
        S2[j] = S2[j] + t2;
      }
      qr += CSTR;
    }
#pragma unroll
    for (int j = 0; j < NC; j++) {
      cost[j] = cost[j] + S0[j];
      cost[j] = cost[j] + S1[j];
      cost[j] = cost[j] + S2[j];
    }
  }
}

// ---------------- init: random candidates + cost + stable sort ----------------
__global__ void init_k(const float* __restrict__ qp, const float* __restrict__ kp,
                       float* __restrict__ cO, int* __restrict__ sO,
                       uint32_t kA0, uint32_t kA1, uint32_t kB0, uint32_t kB1) {
  int idx = blockIdx.x * blockDim.x + threadIdx.x;
  if (idx >= 2 * NPIX) return;
  int b = idx >> 16, p = idx & 0xFFFF;
  int y = p >> 8, x = p & 255;
  uint32_t k0 = b ? kB0 : kA0, k1 = b ? kB1 : kA1;
  // fold_in(key, 10000/10001), then randint does k1,k2 = split(key);
  // span=256 -> multiplier 0 -> only lower_bits (from k2 = enc(fold,(0,1))) used.
  uint32_t f0, f1, ky0, ky1, kx0, kx1;
  tf2x32(k0, k1, 0u, 10000u, f0, f1);
  tf2x32(f0, f1, 0u, 1u, ky0, ky1);        // k2 of split(fold_in(key,10000))
  tf2x32(k0, k1, 0u, 10001u, f0, f1);
  tf2x32(f0, f1, 0u, 1u, kx0, kx1);        // k2 of split(fold_in(key,10001))
  const float* qpb = qp + (size_t)b * CH * CSTR;
  const float* kpb = kp + (size_t)b * CH * CSTR;
  int sy[KK], sx[KK];
#pragma unroll
  for (int j = 0; j < KK; j++) {
    uint32_t cand = (uint32_t)(j * NPIX + p);  // flat idx into (K,H,W)
    sy[j] = (int)(tfbits(ky0, ky1, cand) & 255u);
    sx[j] = (int)(tfbits(kx0, kx1, cand) & 255u);
  }
  float c[KK];
  patch_cost_multi<KK>(qpb, kpb, y, x, sy, sx, c);
  int s[KK];
#pragma unroll
  for (int j = 0; j < KK; j++) s[j] = (sy[j] << 8) | sx[j];
  // stable odd-even transposition sort (ascending cost; ties keep lower index)
#pragma unroll
  for (int ph = 0; ph < KK; ph++) {
#pragma unroll
    for (int i = (ph & 1); i + 1 < KK; i += 2) {
      if (c[i] > c[i + 1]) {
        float tc = c[i]; c[i] = c[i + 1]; c[i + 1] = tc;
        int ts = s[i]; s[i] = s[i + 1]; s[i + 1] = ts;
      }
    }
  }
#pragma unroll
  for (int j = 0; j < KK; j++) {
    cO[(b * KK + j) * NPIX + p] = c[j];
    sO[(b * KK + j) * NPIX + p] = s[j];
  }
}

// ---------------- one PatchMatch iteration ----------------
__global__ void iter_k(const float* __restrict__ qp, const float* __restrict__ kp,
                       const float* __restrict__ cI, const int* __restrict__ sI,
                       float* __restrict__ cO, int* __restrict__ sO,
                       int it, uint32_t kA0, uint32_t kA1, uint32_t kB0, uint32_t kB1) {
  int idx = blockIdx.x * blockDim.x + threadIdx.x;
  if (idx >= 2 * NPIX) return;
  int b = idx >> 16, p = idx & 0xFFFF;
  int y = p >> 8, x = p & 255;
  uint32_t k0 = b ? kB0 : kA0, k1 = b ? kB1 : kA1;
  uint32_t kit0, kit1;
  tf2x32(k0, k1, 0u, (uint32_t)it, kit0, kit1);  // kit = fold_in(key, it)

  // For each randint: kf = fold_in(kit, r); h-key = enc(kf,(0,0)), l-key = enc(kf,(0,1))
  uint32_t hy0k0, hy0k1, ly0k0, ly0k1;  // dy rad=128
  uint32_t hx0k0, hx0k1, lx0k0, lx0k1;  // dx rad=128
  uint32_t hy1k0, hy1k1, ly1k0, ly1k1;  // dy rad=64
  uint32_t hx1k0, hx1k1, lx1k0, lx1k1;  // dx rad=64
  {
    uint32_t f0, f1;
    tf2x32(kit0, kit1, 0u, 0u, f0, f1);
    tf2x32(f0, f1, 0u, 0u, hy0k0, hy0k1);
    tf2x32(f0, f1, 0u, 1u, ly0k0, ly0k1);
    tf2x32(kit0, kit1, 0u, 1u, f0, f1);
    tf2x32(f0, f1, 0u, 0u, hx0k0, hx0k1);
    tf2x32(f0, f1, 0u, 1u, lx0k0, lx0k1);
    tf2x32(kit0, kit1, 0u, 2u, f0, f1);
    tf2x32(f0, f1, 0u, 0u, hy1k0, hy1k1);
    tf2x32(f0, f1, 0u, 1u, ly1k0, ly1k1);
    tf2x32(kit0, kit1, 0u, 3u, f0, f1);
    tf2x32(f0, f1, 0u, 0u, hx1k0, hx1k1);
    tf2x32(f0, f1, 0u, 1u, lx1k0, lx1k1);
  }

  const float* qpb = qp + (size_t)b * CH * CSTR;
  const float* kpb = kp + (size_t)b * CH * CSTR;

  float c14[KK + 6];
  int s14[KK + 6];
  int base = b * KK * NPIX;
#pragma unroll
  for (int j = 0; j < KK; j++) {
    c14[j] = cI[base + j * NPIX + p];
    s14[j] = sI[base + j * NPIX + p];
  }

  // propagation candidates (jnp.roll wraps)
  int pl = (y << 8) | ((x + HW - 1) & (HW - 1));
  int pr = (y << 8) | ((x + 1) & (HW - 1));
  int pu = (((y + HW - 1) & (HW - 1)) << 8) | x;
  int pd = (((y + 1) & (HW - 1)) << 8) | x;
  int svl = sI[base + pl], svr = sI[base + pr];
  int svu = sI[base + pu], svd = sI[base + pd];
  int svc = sI[base + p];
  int nsy[6], nsx[6];
  nsy[0] = svl >> 8;        nsx[0] = (svl & 255) + 1;
  nsy[1] = svr >> 8;        nsx[1] = (svr & 255) - 1;
  nsy[2] = (svu >> 8) + 1;  nsx[2] = svu & 255;
  nsy[3] = (svd >> 8) - 1;  nsx[3] = svd & 255;
  int by = svc >> 8, bx = svc & 255;

  // random-search: randint(-rad, rad+1), SPLIT-key bias correction
  //   span 257 (rad=128): mult=1  -> off = ((hi%257)+(lo%257)) % 257
  //   span 129 (rad=64):  mult=16 -> off = ((hi%129)*16+(lo%129)) % 129
  uint32_t e = (uint32_t)p;
  uint32_t hi, lo;
  hi = tfbits(hy0k0, hy0k1, e); lo = tfbits(ly0k0, ly0k1, e);
  nsy[4] = by + (-128 + (int)(((hi % 257u) + (lo % 257u)) % 257u));
  hi = tfbits(hx0k0, hx0k1, e); lo = tfbits(lx0k0, lx0k1, e);
  nsx[4] = bx + (-128 + (int)(((hi % 257u) + (lo % 257u)) % 257u));
  hi = tfbits(hy1k0, hy1k1, e); lo = tfbits(ly1k0, ly1k1, e);
  nsy[5] = by + (-64 + (int)((((hi % 129u) * 16u) + (lo % 129u)) % 129u));
  hi = tfbits(hx1k0, hx1k1, e); lo = tfbits(lx1k0, lx1k1, e);
  nsx[5] = bx + (-64 + (int)((((hi % 129u) * 16u) + (lo % 129u)) % 129u));

#pragma unroll
  for (int j = 0; j < 6; j++) {
    nsy[j] = min(max(nsy[j], 0), HW - 1);
    nsx[j] = min(max(nsx[j], 0), HW - 1);
  }
  float nc[6];
  patch_cost_multi<6>(qpb, kpb, y, x, nsy, nsx, nc);
#pragma unroll
  for (int j = 0; j < 6; j++) {
    c14[KK + j] = nc[j];
    s14[KK + j] = (nsy[j] << 8) | nsx[j];
  }

  // stable odd-even transposition sort of 14 (== lax.top_k tie semantics)
#pragma unroll
  for (int ph = 0; ph < 14; ph++) {
#pragma unroll
    for (int i = (ph & 1); i + 1 < 14; i += 2) {
      if (c14[i] > c14[i + 1]) {
        float tc = c14[i]; c14[i] = c14[i + 1]; c14[i + 1] = tc;
        int ts = s14[i]; s14[i] = s14[i + 1]; s14[i + 1] = ts;
      }
    }
  }
#pragma unroll
  for (int j = 0; j < KK; j++) {
    cO[base + j * NPIX + p] = c14[j];
    sO[base + j * NPIX + p] = s14[j];
  }
}

// ---------------- softmax attention gather ----------------
__global__ void attn_k(const float* __restrict__ v, const float* __restrict__ cI,
                       const int* __restrict__ sI, float* __restrict__ out) {
  int idx = blockIdx.x * blockDim.x + threadIdx.x;
  if (idx >= 2 * NPIX) return;
  int b = idx >> 16, p = idx & 0xFFFF;
  int base = b * KK * NPIX;
  float c[KK];
  int off[KK];
#pragma unroll
  for (int j = 0; j < KK; j++) {
    c[j] = cI[base + j * NPIX + p];
    off[j] = sI[base + j * NPIX + p];  // (sy<<8)|sx == sy*256+sx
  }
  float m = c[0];  // sorted ascending -> min cost; softmax max of (-cost) = -m
  float w[KK];
  float Z = 0.f;
#pragma unroll
  for (int j = 0; j < KK; j++) { w[j] = expf(m - c[j]); Z = Z + w[j]; }
#pragma unroll
  for (int j = 0; j < KK; j++) w[j] = w[j] / Z;
  const float* vb = v + (size_t)b * CVN * NPIX;
  float* ob = out + (size_t)b * CVN * NPIX;
  for (int cv = 0; cv < CVN; cv++) {
    const float* vc = vb + cv * NPIX;
    float acc = 0.f;
#pragma unroll
    for (int j = 0; j < KK; j++) acc = acc + w[j] * vc[off[j]];
    ob[cv * NPIX + p] = acc;
  }
}

extern "C" void kernel_launch(void* const* d_in, const int* in_sizes, int n_in,
                              void* d_out, int out_size, void* d_ws, size_t ws_size,
                              hipStream_t stream) {
  const float* q = (const float*)d_in[0];
  const float* k = (const float*)d_in[1];
  const float* v = (const float*)d_in[2];
  float* out = (float*)d_out;

  // base key: jax.random.key(42) -> (0,42); split (partitionable/fold-like):
  // keys[i] = threefry(base, (0, i))
  uint32_t kA0, kA1, kB0, kB1;
  tf2x32(0u, 42u, 0u, 0u, kA0, kA1);
  tf2x32(0u, 42u, 0u, 1u, kB0, kB1);

  // workspace layout (floats): qpad | kpad | costA | costB | sA | sB  (~55 MB)
  float* qp = (float*)d_ws;
  float* kp = qp + (size_t)2 * CH * CSTR;
  float* cA = kp + (size_t)2 * CH * CSTR;
  float* cB = cA + (size_t)2 * KK * NPIX;
  int* sA = (int*)(cB + (size_t)2 * KK * NPIX);
  int* sB = sA + (size_t)2 * KK * NPIX;

  const int padTotal = 2 * CH * CSTR;
  pad_k<<<(padTotal + 255) / 256, 256, 0, stream>>>(q, k, qp, kp);
  init_k<<<(2 * NPIX) / 256, 256, 0, stream>>>(qp, kp, cA, sA, kA0, kA1, kB0, kB1);

  float* ci = cA; int* si = sA;
  float* co = cB; int* so = sB;
  for (int it = 0; it < 5; ++it) {
    iter_k<<<(2 * NPIX) / 256, 256, 0, stream>>>(qp, kp, ci, si, co, so, it,
                                                 kA0, kA1, kB0, kB1);
    float* tc = ci; ci = co; co = tc;
    int* ts = si; si = so; so = ts;
  }
  attn_k<<<(2 * NPIX) / 256, 256, 0, stream>>>(v, ci, si, out);
}